// Round 8
// baseline (189.983 us; speedup 1.0000x reference)
//
#include <hip/hip_runtime.h>
#include <hip/hip_bf16.h>
#include <stdint.h>

// Router: logits = x @ wg^T + gr @ gm^T ; std-normalized softmax; top-2;
// zero expert 7; renormalize. Outputs flat: gates[T,2] | indices[T,2] (as
// float) | logits[T,8].  T=16384, D=2048, E=8.
//
// R8 = R7 split-K + PERFECT OCCUPANCY BALANCE + deeper prefetch.
//  Evidence: read-side ops on this box all sit ~3 TB/s (restore copy 3.1,
//  m13 copy 3.15/dir, kernels 2.2-2.7) -> kernel floor ~45us. R5's
//  measured 25.8% occupancy vs 50% expected exposed a residency tail:
//  1024-block grid at 3-blocks/CU capacity runs 768 then 256 blocks
//  (~25% waste) — matching the 60-vs-45us gap.
//  Fix: grid = 512 blocks (exactly 2/CU, resident even at 256 VGPR),
//  wave grid-strides 2 strips of 32 tokens; batch-granular ping-pong
//  (8-load nt bursts, up to 16 outstanding); 256-reg cap, ~180 live.
//  Kernel 2 (proven): lane sums 8 col-group partials + epilogue.

#define DCONST 2048

typedef float f32x4 __attribute__((ext_vector_type(4)));

__device__ __forceinline__ unsigned long long shfl_xor_u64(unsigned long long v, int m) {
    int lo = __shfl_xor((int)(uint32_t)v, m, 64);
    int hi = __shfl_xor((int)(uint32_t)(v >> 32), m, 64);
    return ((unsigned long long)(uint32_t)hi << 32) | (unsigned long long)(uint32_t)lo;
}

// ---------------- Kernel 1: split-K partial GEMM ----------------
__global__ __launch_bounds__(256, 2)
void router_gemm(const float* __restrict__ x,   // [T,2048]
                 const float* __restrict__ wg,  // [8,2048]
                 float* __restrict__ ws,        // [T/8][8][64] partials
                 int T)
{
    const int wave = threadIdx.x >> 6;
    const int lane = threadIdx.x & 63;
    const int W    = blockIdx.x * 4 + wave;          // 0..2047

    #pragma unroll 1
    for (int s = 0; s < 2; ++s) {
        const int id    = W + s * 2048;              // 0..4095
        const int g     = id & 7;                    // column group (256 cols)
        const int trow  = (id >> 3) * 32;            // first of 32 tokens
        const int tb0   = trow >> 3;

        // wg slice for this lane's 4 columns, all 8 experts (L2-hot)
        const float* wgp = wg + g * 256 + (lane << 2);
        f32x4 w8[8];
        #pragma unroll
        for (int e = 0; e < 8; ++e)
            w8[e] = *(const f32x4*)(wgp + (size_t)e * DCONST);

        const float* xp = x + (size_t)trow * DCONST + g * 256 + (lane << 2);

        f32x4 A[8], B[8];

        #define LOADB(buf, b)                                                 \
            { _Pragma("unroll")                                               \
              for (int i = 0; i < 8; ++i)                                     \
                  buf[i] = __builtin_nontemporal_load(                        \
                      (const f32x4*)(xp + (size_t)((b) * 8 + i) * DCONST)); }

        #define DOBATCH(buf, b)                                               \
            { float acc[64];                                                  \
              _Pragma("unroll")                                               \
              for (int v = 0; v < 64; ++v) acc[v] = 0.f;                      \
              _Pragma("unroll")                                               \
              for (int i = 0; i < 8; ++i) {                                   \
                  _Pragma("unroll")                                           \
                  for (int e = 0; e < 8; ++e) {                               \
                      float a = acc[i * 8 + e];                               \
                      a += buf[i].x * w8[e].x;                                \
                      a += buf[i].y * w8[e].y;                                \
                      a += buf[i].z * w8[e].z;                                \
                      a += buf[i].w * w8[e].w;                                \
                      acc[i * 8 + e] = a;                                     \
                  }                                                           \
              }                                                               \
              _Pragma("unroll")                                               \
              for (int m = 1; m < 64; m <<= 1) {                              \
                  const bool up = (lane & m) != 0;                            \
                  _Pragma("unroll")                                           \
                  for (int v = 0; v < 64; v += 2 * m) {                       \
                      const float keep = up ? acc[v + m] : acc[v];            \
                      const float send = up ? acc[v] : acc[v + m];            \
                      const float got  = __shfl_xor(send, m, 64);             \
                      acc[v] = keep + got;                                    \
                  }                                                           \
              }                                                               \
              ws[(size_t)(tb0 + (b)) * 512 + g * 64 + lane] = acc[0]; }

        LOADB(A, 0);
        #pragma unroll 1
        for (int b = 0; b < 4; b += 2) {
            LOADB(B, b + 1);           // 16 outstanding
            DOBATCH(A, b);             // waits A; B stays in flight
            if (b + 2 < 4) LOADB(A, b + 2);
            DOBATCH(B, b + 1);
        }
    }
}

// ---------------- Kernel 2: reduce + epilogue ----------------
__global__ __launch_bounds__(256)
void router_epilogue(const float* __restrict__ ws,  // [T/8][8][64]
                     const float* __restrict__ gm,  // [8,8]
                     const float* __restrict__ gr,  // [T,8]
                     float* __restrict__ out,       // 2T gates | 2T idx | 8T logits
                     int T)
{
    const int wave = threadIdx.x >> 6;
    const int lane = threadIdx.x & 63;
    const int tb   = blockIdx.x * 4 + wave;    // [0, T/8)
    const int t0   = tb * 8;

    float logit = 0.f;
    #pragma unroll
    for (int g = 0; g < 8; ++g)
        logit += ws[(size_t)tb * 512 + g * 64 + lane];

    const int tt = lane >> 3;
    const int f  = lane & 7;
    const int t  = t0 + tt;

    // residual: logit += sum_e gr[t][e] * gm[f][e]
    const float4 ga = *(const float4*)(gr + (size_t)t * 8);
    const float4 gb = *(const float4*)(gr + (size_t)t * 8 + 4);
    const float4 ma = *(const float4*)(gm + f * 8);
    const float4 mb = *(const float4*)(gm + f * 8 + 4);
    logit += ga.x * ma.x + ga.y * ma.y + ga.z * ma.z + ga.w * ma.w
           + gb.x * mb.x + gb.y * mb.y + gb.z * mb.z + gb.w * mb.w;

    // logits output (offset 4T), contiguous per wave
    out[(size_t)4 * T + (size_t)t0 * 8 + lane] = logit;

    // stats over the 8-lane expert group
    float s = logit;
    s += __shfl_xor(s, 1, 64);
    s += __shfl_xor(s, 2, 64);
    s += __shfl_xor(s, 4, 64);
    const float mean = s * 0.125f;
    float d2 = (logit - mean) * (logit - mean);
    d2 += __shfl_xor(d2, 1, 64);
    d2 += __shfl_xor(d2, 2, 64);
    d2 += __shfl_xor(d2, 4, 64);
    const float stdv = sqrtf(d2 / 7.0f);    // ddof=1

    // top-2 via order-preserving 64-bit keys; ties -> smaller index
    uint32_t ob = __float_as_uint(logit);
    ob = (ob & 0x80000000u) ? ~ob : (ob | 0x80000000u);
    unsigned long long k1 = ((unsigned long long)ob << 8) | (unsigned long long)(7 - f);
    unsigned long long k2 = 0ull;
    #pragma unroll
    for (int m = 1; m <= 4; m <<= 1) {
        const unsigned long long o1 = shfl_xor_u64(k1, m);
        const unsigned long long o2 = shfl_xor_u64(k2, m);
        const unsigned long long hi = k1 > o1 ? k1 : o1;
        const unsigned long long lo = k1 > o1 ? o1 : k1;
        const unsigned long long so = k2 > o2 ? k2 : o2;
        k1 = hi;
        k2 = lo > so ? lo : so;
    }
    const int i1 = 7 - (int)(k1 & 0xFFull);
    const int i2 = 7 - (int)(k2 & 0xFFull);
    uint32_t b1 = (uint32_t)(k1 >> 8), b2 = (uint32_t)(k2 >> 8);
    b1 = (b1 & 0x80000000u) ? (b1 ^ 0x80000000u) : ~b1;
    b2 = (b2 & 0x80000000u) ? (b2 ^ 0x80000000u) : ~b2;
    const float l1 = __uint_as_float(b1);
    const float l2 = __uint_as_float(b2);

    // gates: softmax + zero-expert-7 + renorm collapses to a sigmoid
    float g0, g1;
    if (i1 == 7)      { g0 = 0.f; g1 = 1.f; }
    else if (i2 == 7) { g0 = 1.f; g1 = 0.f; }
    else {
        const float p = 1.0f / (1.0f + __expf(-(l1 - l2) / stdv));
        g0 = p; g1 = 1.0f - p;
    }

    if (f == 0) out[(size_t)2 * t]             = g0;
    if (f == 1) out[(size_t)2 * t + 1]         = g1;
    if (f == 2) out[(size_t)2 * T + 2 * t]     = (float)i1;
    if (f == 3) out[(size_t)2 * T + 2 * t + 1] = (float)i2;
}

extern "C" void kernel_launch(void* const* d_in, const int* in_sizes, int n_in,
                              void* d_out, int out_size, void* d_ws, size_t ws_size,
                              hipStream_t stream) {
    const float* x  = (const float*)d_in[0];
    const float* wg = (const float*)d_in[1];
    const float* gm = (const float*)d_in[2];
    const float* gr = (const float*)d_in[3];
    float* ws = (float*)d_ws;                  // needs T/8*512*4 = 4 MB
    const int T = in_sizes[0] / DCONST;        // 16384

    router_gemm<<<512, 256, 0, stream>>>(x, wg, ws, T);       // 2 blocks/CU exact

    const int epi_blocks = T / 32;                            // 512
    router_epilogue<<<epi_blocks, 256, 0, stream>>>(ws, gm, gr, (float*)d_out, T);
}